// Round 6
// baseline (375.724 us; speedup 1.0000x reference)
//
#include <hip/hip_runtime.h>
#include <math.h>

// Problem constants (fixed by the reference file)
#define BATCH 16
#define CHAN  64
#define Hh    256
#define Ww    256
#define HP    128     // pooled H
#define WP    128     // pooled W
#define TH    64      // output tile rows per block
#define TW    64      // output tile cols per block
#define PR    34      // staged pooled region side (covers tile + 1-cell halo)

typedef float vfloat4 __attribute__((ext_vector_type(4)));

// One block = one 64x64 output tile. 256 threads; thread owns a 4x4 output
// block and computes its 6x6 canvas patch ENTIRELY IN REGISTERS:
//   - LDS holds only the staged 34x34 pooled (prov, f-bits) pair tile.
//   - Canvas cell (R,C) candidate sources: i in {R/2-1, R/2} (even R) or
//     {(R-1)/2} (odd R); same for columns. Thread's 6x6 patch needs a 4x4
//     pooled patch. Scatter is replayed per-cell as a cndmask chain in
//     ascending flat-index (q) order -> last match wins = numpy semantics.
//   - Image-edge staging clamps duplicate a neighboring row/col; a duplicate
//     replays that row in identical candidate order (before the original on
//     the low side, after it on the high side), so the final winner value is
//     unchanged -> no validity masks needed.
//   - Out-of-image canvas cells (reduce_window padding) forced to -inf after
//     the winner pass; no prov value can target them (prov is clipped
//     in-image) so late forcing is safe.
// One barrier total; zero LDS atomics; zero canvas init.
__global__ __launch_bounds__(256, 4) void unpool_dilate_kernel(
    const float* __restrict__ f, const int* __restrict__ prov,
    float* __restrict__ out)
{
    __shared__ __align__(16) int2 sp[PR * PR];   // (prov, f-bits) pairs: 9248 B

    const int tid = threadIdx.x;
    const int bc  = blockIdx.y;                  // 0..1023 (b*C + c)
    const int ty  = blockIdx.x >> 2;             // 4x4 tiles per image
    const int tx  = blockIdx.x & 3;
    const int y0  = ty * TH;
    const int x0  = tx * TW;
    const int pi_base = (y0 >> 1) - 1;           // staged row 0 -> pooled i (may be -1)
    const int pj_base = (x0 >> 1) - 1;
    const size_t in_base = (size_t)bc * (HP * WP);

    // ---- stage pooled (prov,f) pairs, coalesced, edge-clamped ----
    #pragma unroll
    for (int it = 0; it < 5; ++it) {
        const int k = tid + it * 256;
        if (k < PR * PR) {
            const int li = k / PR;               // compile-time magic mul
            const int lj = k - li * PR;
            const int i  = min(max(pi_base + li, 0), HP - 1);
            const int j  = min(max(pj_base + lj, 0), WP - 1);
            const size_t g = in_base + (size_t)(i * WP + j);
            sp[k] = make_int2(prov[g], __float_as_int(f[g]));
        }
    }
    __syncthreads();

    // ---- per-thread 4x4 pooled candidate patch (8 x ds_read_b128) ----
    const int tr = tid >> 4;                     // 0..15
    const int tc = tid & 15;                     // 0..15
    const int r0 = y0 + 4 * tr;                  // first owned output row
    const int c0 = x0 + 4 * tc;
    const int base_rel = (r0 - 1) * 256 + (c0 - 1);  // image idx of canvas (0,0)

    int   pr_[4][4];
    float fv[4][4];
    #pragma unroll
    for (int d = 0; d < 4; ++d) {
        const int rb = (2 * tr + d) * PR + 2 * tc;   // pair idx, always even -> 16B aligned
        const int4 pA = *(const int4*)&sp[rb];       // pairs e=0,1
        const int4 pB = *(const int4*)&sp[rb + 2];   // pairs e=2,3
        pr_[d][0] = pA.x - base_rel; fv[d][0] = __int_as_float(pA.y);
        pr_[d][1] = pA.z - base_rel; fv[d][1] = __int_as_float(pA.w);
        pr_[d][2] = pB.x - base_rel; fv[d][2] = __int_as_float(pB.y);
        pr_[d][3] = pB.z - base_rel; fv[d][3] = __int_as_float(pB.w);
    }

    // ---- winner pass: replay scatter in q order into 6x6 register canvas ----
    float val[6][6];
    #pragma unroll
    for (int a = 0; a < 6; ++a)
        #pragma unroll
        for (int b = 0; b < 6; ++b) val[a][b] = 0.0f;

    // candidate slot d can target canvas rows a in [ALO[d], AHI[d]] (a = 2d-1+dy)
    constexpr int ALO[4] = {0, 1, 3, 5};
    constexpr int AHI[4] = {1, 3, 5, 5};
    #pragma unroll
    for (int d = 0; d < 4; ++d) {
        #pragma unroll
        for (int e = 0; e < 4; ++e) {
            const int   prel = pr_[d][e];
            const float fc   = fv[d][e];
            #pragma unroll
            for (int a = ALO[d]; a <= AHI[d]; ++a) {
                #pragma unroll
                for (int b = ALO[e]; b <= AHI[e]; ++b) {
                    val[a][b] = (prel == a * 256 + b) ? fc : val[a][b];
                }
            }
        }
    }

    // ---- out-of-image canvas cells -> -inf (reduce_window 'same' padding) ----
    {
        const bool e0 = (r0 == 0), e5 = (r0 == Hh - 4);
        const bool g0 = (c0 == 0), g5 = (c0 == Ww - 4);
        #pragma unroll
        for (int b = 0; b < 6; ++b) {
            val[0][b] = e0 ? -INFINITY : val[0][b];
            val[5][b] = e5 ? -INFINITY : val[5][b];
        }
        #pragma unroll
        for (int a = 0; a < 6; ++a) {
            val[a][0] = g0 ? -INFINITY : val[a][0];
            val[a][5] = g5 ? -INFINITY : val[a][5];
        }
    }

    // ---- 3x3 dilation: vertical max3 then horizontal max3; 4 b128 stores ----
    const size_t obase = (size_t)bc * (Hh * Ww) + (size_t)r0 * Ww + c0;
    #pragma unroll
    for (int p = 0; p < 4; ++p) {
        float m[6];
        #pragma unroll
        for (int b = 0; b < 6; ++b)
            m[b] = fmaxf(fmaxf(val[p][b], val[p + 1][b]), val[p + 2][b]);  // v_max3
        vfloat4 res;
        res.x = fmaxf(fmaxf(m[0], m[1]), m[2]);
        res.y = fmaxf(fmaxf(m[1], m[2]), m[3]);
        res.z = fmaxf(fmaxf(m[2], m[3]), m[4]);
        res.w = fmaxf(fmaxf(m[3], m[4]), m[5]);
        __builtin_nontemporal_store(res, (vfloat4*)(out + obase + (size_t)p * Ww));
    }
}

extern "C" void kernel_launch(void* const* d_in, const int* in_sizes, int n_in,
                              void* d_out, int out_size, void* d_ws, size_t ws_size,
                              hipStream_t stream) {
    const float* f    = (const float*)d_in[0];
    const int*   prov = (const int*)d_in[1];
    // d_in[2]=h, d_in[3]=w fixed at 256 by the reference; hardcoded.
    float* out = (float*)d_out;

    dim3 grid((Hh / TH) * (Ww / TW), BATCH * CHAN);  // (16, 1024)
    unpool_dilate_kernel<<<grid, 256, 0, stream>>>(f, prov, out);
}

// Round 7
// 364.351 us; speedup vs baseline: 1.0312x; 1.0312x over previous
//
#include <hip/hip_runtime.h>
#include <math.h>

// Problem constants (fixed by the reference file)
#define BATCH 16
#define CHAN  64
#define Hh    256
#define Ww    256
#define HP    128     // pooled H
#define WP    128     // pooled W
#define TH    64      // output tile rows per block
#define TW    64      // output tile cols per block
#define CH    66      // canvas rows (halo 1)
#define CW    66      // canvas cols
#define CS    68      // canvas row stride in words (keeps 16B alignment)

typedef unsigned int u32;
typedef float vfloat4 __attribute__((ext_vector_type(4)));

// One block = one 64x64 output tile of one (b,c) image. 256 threads.
//
// XCD swizzle: MI355X dispatches blocks round-robin across 8 XCDs
// (xcd = dispatch_index % 8), and per-XCD L2s are private. The 4 tx-tiles of
// one (bc,ty) strip read overlapping pooled-row cache lines; remap work so
// those 4 tiles get dispatch indices differing by exactly 8 -> same XCD,
// within 32 slots -> temporally close -> halo lines hit local L2 once.
//
// Single u32 LDS canvas, three phases:
//   phase 0: init 0 (in-image) / 0xFF800000 (-inf, reduce_window padding).
//   phase 1: branchless pipelined loads of prov+f (clamped addresses, validity
//            mask in registers), then atomicMax(cell, q+1); winner = max flat
//            pooled index q = numpy last-write-wins scatter semantics.
//   phase 2: winner (cell == q+1) overwrites cell with its f32 bits. Every
//            keyed cell has exactly one winner, so no key survives. Race
//            safety: float bits of N(0,1) values are never in [1,16385]
//            (that range is denormals ~1e-41), so a loser can't mistake a
//            value for its key.
//   stage 2: 3x3 windowed max; each thread owns a 4x4 output block, reads a
//            6x6 f32 patch (2.25 LDS words/px), nontemporal float4 stores.
__global__ __launch_bounds__(256, 8) void unpool_dilate_kernel(
    const float* __restrict__ f, const int* __restrict__ prov,
    float* __restrict__ out)
{
    __shared__ __align__(16) u32 s[CH * CS];   // 4488 words = 17.95 KB

    const int tid = threadIdx.x;

    // ---- XCD-aware work remap (bijection over 16384 blocks) ----
    const int n   = blockIdx.x + (int)gridDim.x * blockIdx.y;  // HW dispatch order (x fast)
    const int k   = n >> 3;
    const int tx  = k & 3;                     // tile col within image
    const int p   = (n & 7) + 8 * (k >> 2);    // strip index: 0..4095
    const int bc  = p >> 2;                    // 0..1023 (b*C + c)
    const int ty  = p & 3;                     // tile row within image
    const int y0  = ty * TH;
    const int x0  = tx * TW;

    // ---- candidate pooled region: up to 34x34, guarded at image edges ----
    const int pi_min = (ty == 0) ? 0 : (ty * 32 - 1);
    const int pj_min = (tx == 0) ? 0 : (tx * 32 - 1);
    const int pi_max = min(HP - 1, ty * 32 + 32);
    const int pj_max = min(WP - 1, tx * 32 + 32);
    const size_t in_base = (size_t)bc * (HP * WP);

    // ---- phase 1a: branchless pipelined loads (issue all 10 loads early) ----
    u32   m_key[5];
    float m_f[5];
    int   m_p[5];
    bool  m_v[5];
    #pragma unroll
    for (int it = 0; it < 5; ++it) {
        const int kk = tid + it * 256;
        const int ki = kk / 34;                // compile-time magic mul
        const int kj = kk - ki * 34;
        m_v[it] = (kk < 34 * 34) & (pi_min + ki <= pi_max) & (pj_min + kj <= pj_max);
        const int pi = min(pi_min + ki, pi_max);   // clamped -> always in-bounds
        const int pj = min(pj_min + kj, pj_max);
        const int q  = pi * WP + pj;
        m_key[it] = (u32)(q + 1);
        m_p[it]   = prov[in_base + q];         // 5 loads, no control flow
        m_f[it]   = f[in_base + q];            // 5 more, addresses independent
    }

    // ---- phase 0: zero-fill (uint4), then -inf borders for edge tiles ----
    {
        uint4* p4 = (uint4*)s;
        const uint4 z = make_uint4(0u, 0u, 0u, 0u);
        #pragma unroll
        for (int it = 0; it < 5; ++it) {
            const int idx = tid + it * 256;
            if (idx < (CH * CS) / 4) p4[idx] = z;
        }
    }
    const u32 NEGINF = 0xFF800000u;
    if (ty == 0 && tid < CW) s[tid] = NEGINF;                    // canvas row 0
    if (ty == 3 && tid < CW) s[(CH - 1) * CS + tid] = NEGINF;    // canvas row 65
    if (tx == 0 && tid < CH) s[tid * CS] = NEGINF;               // canvas col 0
    if (tx == 3 && tid < CH) s[tid * CS + (CW - 1)] = NEGINF;    // canvas col 65
    __syncthreads();

    // ---- phase 1b: atomicMax keys ----
    int m_li[5];
    #pragma unroll
    for (int it = 0; it < 5; ++it) {
        const int pp = m_p[it];
        const int lr = (pp >> 8) - y0 + 1;     // Ww == 256
        const int lc = (pp & 255) - x0 + 1;
        if (m_v[it] && (unsigned)lr < CH && (unsigned)lc < CW) {
            const int li = lr * CS + lc;
            m_li[it] = li;
            atomicMax(&s[li], m_key[it]);
        } else {
            m_li[it] = -1;
        }
    }
    __syncthreads();

    // ---- phase 2: winners overwrite their key with the f32 value bits ----
    #pragma unroll
    for (int it = 0; it < 5; ++it) {
        if (m_li[it] >= 0 && s[m_li[it]] == m_key[it])
            s[m_li[it]] = __float_as_uint(m_f[it]);
    }
    __syncthreads();

    // ---- stage 2: 3x3 max; thread owns 4x4 outputs, reads 6x6 patch ----
    const float* sf = (const float*)s;
    const int tr = tid >> 4;                  // 0..15
    const int tc = tid & 15;                  // 0..15
    const int r0 = 4 * tr;                    // canvas row base (== output row)
    const int c0 = 4 * tc;

    float h0[4], h1[4];                       // horizontal 3-max of prior rows
    const size_t obase = (size_t)bc * (Hh * Ww) + (size_t)(y0 + r0) * Ww + (x0 + c0);

    #pragma unroll
    for (int r = 0; r < 6; ++r) {
        const float* row = sf + (r0 + r) * CS + c0;
        const float4 a = *(const float4*)row;        // cols c0..c0+3 (16B aligned)
        const float2 b = *(const float2*)(row + 4);  // cols c0+4..c0+5
        float h[4];
        h[0] = fmaxf(fmaxf(a.x, a.y), a.z);          // -> v_max3_f32
        h[1] = fmaxf(fmaxf(a.y, a.z), a.w);
        h[2] = fmaxf(fmaxf(a.z, a.w), b.x);
        h[3] = fmaxf(fmaxf(a.w, b.x), b.y);
        if (r >= 2) {
            vfloat4 res;
            res.x = fmaxf(fmaxf(h0[0], h1[0]), h[0]);
            res.y = fmaxf(fmaxf(h0[1], h1[1]), h[1]);
            res.z = fmaxf(fmaxf(h0[2], h1[2]), h[2]);
            res.w = fmaxf(fmaxf(h0[3], h1[3]), h[3]);
            __builtin_nontemporal_store(res, (vfloat4*)(out + obase + (size_t)(r - 2) * Ww));
        }
        #pragma unroll
        for (int j = 0; j < 4; ++j) { h0[j] = h1[j]; h1[j] = h[j]; }
    }
}

extern "C" void kernel_launch(void* const* d_in, const int* in_sizes, int n_in,
                              void* d_out, int out_size, void* d_ws, size_t ws_size,
                              hipStream_t stream) {
    const float* f    = (const float*)d_in[0];
    const int*   prov = (const int*)d_in[1];
    // d_in[2]=h, d_in[3]=w fixed at 256 by the reference; hardcoded.
    float* out = (float*)d_out;

    dim3 grid((Hh / TH) * (Ww / TW), BATCH * CHAN);  // (16, 1024)
    unpool_dilate_kernel<<<grid, 256, 0, stream>>>(f, prov, out);
}